// Round 6
// baseline (411.448 us; speedup 1.0000x reference)
//
#include <hip/hip_runtime.h>

using short8 = __attribute__((ext_vector_type(8))) short;
using f32x16 = __attribute__((ext_vector_type(16))) float;
using bf16x2 = __attribute__((ext_vector_type(2))) __bf16;

__device__ __forceinline__ short b16(float f) {
  __bf16 h = (__bf16)f;
  return __builtin_bit_cast(short, h);
}
// packed pair -> compiler emits v_cvt_pk_bf16_f32
__device__ __forceinline__ unsigned pk2(float lo, float hi) {
  bf16x2 t; t[0] = (__bf16)lo; t[1] = (__bf16)hi;
  return __builtin_bit_cast(unsigned, t);
}
__device__ __forceinline__ short8 pack8(const float4& a, const float4& b) {
  uint4 u;
  u.x = pk2(a.x, a.y); u.y = pk2(a.z, a.w);
  u.z = pk2(b.x, b.y); u.w = pk2(b.z, b.w);
  return __builtin_bit_cast(short8, u);
}
__device__ __forceinline__ float bf2f(unsigned short u) {
  return __builtin_bit_cast(float, ((unsigned)u) << 16);
}

// Kernel 1: W' = softmax(weight_mat / softplus(tau)) * 0.125, bf16 out (row-major)
__global__ __launch_bounds__(256) void w_softmax_kernel(
    const float* __restrict__ wm, const float* __restrict__ tau,
    unsigned short* __restrict__ wout) {
  const int row = blockIdx.x;
  const int tid = threadIdx.x;
  const float sp  = log1pf(__expf(tau[row]));
  const float inv = 1.0f / sp;
  const float4* src = (const float4*)(wm + (size_t)row * 1024);
  float4 v = src[tid];
  float v0 = v.x * inv, v1 = v.y * inv, v2 = v.z * inv, v3 = v.w * inv;
  float mx = fmaxf(fmaxf(v0, v1), fmaxf(v2, v3));
  #pragma unroll
  for (int m = 1; m < 64; m <<= 1) mx = fmaxf(mx, __shfl_xor(mx, m));
  __shared__ float red[8];
  const int wv = tid >> 6;
  if ((tid & 63) == 0) red[wv] = mx;
  __syncthreads();
  mx = fmaxf(fmaxf(red[0], red[1]), fmaxf(red[2], red[3]));
  float e0 = __expf(v0 - mx), e1 = __expf(v1 - mx);
  float e2 = __expf(v2 - mx), e3 = __expf(v3 - mx);
  float s = e0 + e1 + e2 + e3;
  #pragma unroll
  for (int m = 1; m < 64; m <<= 1) s += __shfl_xor(s, m);
  if ((tid & 63) == 0) red[4 + wv] = s;
  __syncthreads();
  s = red[4] + red[5] + red[6] + red[7];
  const float r = 0.125f / s;
  uint2 o; o.x = pk2(e0 * r, e1 * r); o.y = pk2(e2 * r, e3 * r);
  *(uint2*)(wout + (size_t)row * 1024 + tid * 4) = o;
}

// Kernel 2: transpose bf16 W' (row-major [q][s]) -> Wt [s][q]. 64x64 tiles.
__global__ __launch_bounds__(256) void w_transpose_kernel(
    const unsigned short* __restrict__ win, unsigned short* __restrict__ wt) {
  __shared__ unsigned short tile[64][73];
  const int ti = blockIdx.x & 15;   // s-tile
  const int tj = blockIdx.x >> 4;   // q-tile
  const int t  = threadIdx.x;
  const int qa = t >> 2;
  const int sb = (t & 3) * 16;
  const unsigned short* src = win + (size_t)(tj * 64 + qa) * 1024 + ti * 64 + sb;
  short8 a0 = *(const short8*)(src);
  short8 a1 = *(const short8*)(src + 8);
  #pragma unroll
  for (int j = 0; j < 8; ++j) { tile[qa][sb + j] = a0[j]; tile[qa][sb + 8 + j] = a1[j]; }
  __syncthreads();
  const int sr = t >> 2;
  const int qb = (t & 3) * 16;
  short8 w0, w1;
  #pragma unroll
  for (int j = 0; j < 8; ++j) { w0[j] = tile[qb + j][sr]; w1[j] = tile[qb + 8 + j][sr]; }
  unsigned short* dst = wt + (size_t)(ti * 64 + sr) * 1024 + tj * 64 + qb;
  *(short8*)(dst) = w0;
  *(short8*)(dst + 8) = w1;
}

// Kernel 3: 32x32 swapped-QK flash attention. 4 waves x 32 q-rows = 128 q/block.
// 4 blocks/CU -> whole 1024-block grid resident (zero tail).
__global__ __launch_bounds__(256, 4) void attn_kernel(
    const float* __restrict__ Q, const float* __restrict__ K,
    const float* __restrict__ V, const unsigned short* __restrict__ Wt,
    float* __restrict__ O) {
  // XCD-bijective swizzle: 8 qblk-blocks sharing one (b,h) -> same XCD.
  const int orig = blockIdx.x;                 // 1024 blocks
  const int xcd  = orig & 7, slot = orig >> 3;
  const int bh   = xcd * 16 + (slot >> 3);
  const int qblk = slot & 7;
  const int b = bh >> 3, h = bh & 7;

  const int tid = threadIdx.x, wv = tid >> 6, lane = tid & 63;
  const int ql = lane & 31, hi = lane >> 5;
  const int qg = qblk * 128 + wv * 32 + ql;

  __shared__ alignas(16) short Ks[2][4096];    // K tile [s][e] bf16, swz (s&7)<<4
  __shared__ alignas(16) short Vt[2][4096];    // V^T tile [d][s] bf16, swz ((d&7)^(d>>3))<<4
  __shared__ float Sc[128];

  // Q B-fragments: lane ql = q, k = es*16 + hi*8 + j
  const float* qrow = Q + ((size_t)(b * 1024 + qg)) * 512 + h * 64;
  short8 qb[4];
  #pragma unroll
  for (int es = 0; es < 4; ++es) {
    float4 f0 = *(const float4*)(qrow + es * 16 + hi * 8);
    float4 f1 = *(const float4*)(qrow + es * 16 + hi * 8 + 4);
    qb[es] = pack8(f0, f1);
  }

  // ---- K staging: thread -> row srow, 16 float cols at cgrp ----
  const int srow = tid >> 2;
  const int cgrp = (tid & 3) * 16;
  const float* kp = K + ((size_t)(b * 1024 + srow)) * 512 + h * 64 + cgrp;
  const int kswz = (srow & 7) << 4;
  const int kwb0 = srow * 128 + ((cgrp * 2) ^ kswz);
  const int kwb1 = srow * 128 + ((cgrp * 2 + 16) ^ kswz);

  // ---- V staging: thread -> 4 s-rows (vs0..+3) x 4 d (vd0..+3) ----
  const int vs0 = (tid >> 4) * 4;     // 0..60
  const int vd0 = (tid & 15) * 4;     // 0..60
  const float* vp = V + ((size_t)(b * 1024 + vs0)) * 512 + h * 64 + vd0;
  int vwoff[4];
  #pragma unroll
  for (int dd = 0; dd < 4; ++dd) {
    const int d = vd0 + dd;
    vwoff[dd] = d * 128 + ((vs0 * 2) ^ ((((d & 7) ^ (d >> 3)) & 7) << 4));
  }

  {   // prologue: stage tile 0 into buffer 0
    float4 a0 = *(const float4*)(kp);
    float4 a1 = *(const float4*)(kp + 4);
    float4 a2 = *(const float4*)(kp + 8);
    float4 a3 = *(const float4*)(kp + 12);
    float4 r0 = *(const float4*)(vp);
    float4 r1 = *(const float4*)(vp + 512);
    float4 r2 = *(const float4*)(vp + 1024);
    float4 r3 = *(const float4*)(vp + 1536);
    *(short8*)((char*)Ks[0] + kwb0) = pack8(a0, a1);
    *(short8*)((char*)Ks[0] + kwb1) = pack8(a2, a3);
    const float vr[4][4] = {{r0.x, r0.y, r0.z, r0.w}, {r1.x, r1.y, r1.z, r1.w},
                            {r2.x, r2.y, r2.z, r2.w}, {r3.x, r3.y, r3.z, r3.w}};
    #pragma unroll
    for (int dd = 0; dd < 4; ++dd) {
      uint2 w; w.x = pk2(vr[0][dd], vr[1][dd]); w.y = pk2(vr[2][dd], vr[3][dd]);
      *(uint2*)((char*)Vt[0] + vwoff[dd]) = w;
    }
  }
  __syncthreads();

  f32x16 o0, o1;
  #pragma unroll
  for (int i = 0; i < 16; ++i) { o0[i] = 0.f; o1[i] = 0.f; }
  float m_r = -INFINITY, l_r = 0.f;

  const unsigned short* wcol = Wt + qg;

  #pragma unroll 1
  for (int kt = 0; kt < 16; ++kt) {
    const int c = kt & 1;
    const int s0 = kt * 64;

    // ---- T14: issue next-tile K/V global loads now, consume at bottom ----
    float4 nk0, nk1, nk2, nk3, nr0, nr1, nr2, nr3;
    if (kt < 15) {
      const size_t soff = (size_t)((kt + 1) * 64) * 512;
      nk0 = *(const float4*)(kp + soff);       nk1 = *(const float4*)(kp + soff + 4);
      nk2 = *(const float4*)(kp + soff + 8);   nk3 = *(const float4*)(kp + soff + 12);
      nr0 = *(const float4*)(vp + soff);       nr1 = *(const float4*)(vp + soff + 512);
      nr2 = *(const float4*)(vp + soff + 1024); nr3 = *(const float4*)(vp + soff + 1536);
    }

    // ---- this tile's w: 32 coalesced ushort loads ----
    unsigned short wu[32];
    #pragma unroll
    for (int st = 0; st < 2; ++st)
      #pragma unroll
      for (int rg = 0; rg < 4; ++rg)
        #pragma unroll
        for (int cc = 0; cc < 4; ++cc)
          wu[st * 16 + rg * 4 + cc] =
              wcol[(size_t)(s0 + st * 32 + rg * 8 + 4 * hi + cc) * 1024];

    // ---- S^T = mfma(K, Q) ----
    f32x16 sa0, sa1;
    #pragma unroll
    for (int i = 0; i < 16; ++i) { sa0[i] = 0.f; sa1[i] = 0.f; }
    {
      const int sr0 = ql, sr1 = 32 + ql;
      const char* kb0 = (const char*)Ks[c] + sr0 * 128;
      const char* kb1 = (const char*)Ks[c] + sr1 * 128;
      const int sz0 = (sr0 & 7) << 4, sz1 = (sr1 & 7) << 4;
      __builtin_amdgcn_s_setprio(1);
      #pragma unroll
      for (int es = 0; es < 4; ++es) {
        short8 ka0 = *(const short8*)(kb0 + ((es * 32 + hi * 16) ^ sz0));
        short8 ka1 = *(const short8*)(kb1 + ((es * 32 + hi * 16) ^ sz1));
        sa0 = __builtin_amdgcn_mfma_f32_32x32x16_bf16(ka0, qb[es], sa0, 0, 0, 0);
        sa1 = __builtin_amdgcn_mfma_f32_32x32x16_bf16(ka1, qb[es], sa1, 0, 0, 0);
      }
      __builtin_amdgcn_s_setprio(0);
    }

    // ---- logits ----
    float lg[32];
    #pragma unroll
    for (int reg = 0; reg < 16; ++reg) {
      lg[reg]      = sa0[reg] * bf2f(wu[reg]);
      lg[16 + reg] = sa1[reg] * bf2f(wu[16 + reg]);
    }

    // ---- max tree + one cross-half shfl ----
    float t16[16];
    #pragma unroll
    for (int i = 0; i < 16; ++i) t16[i] = fmaxf(lg[i], lg[i + 16]);
    float t8[8];
    #pragma unroll
    for (int i = 0; i < 8; ++i) t8[i] = fmaxf(t16[i], t16[i + 8]);
    float t4[4];
    #pragma unroll
    for (int i = 0; i < 4; ++i) t4[i] = fmaxf(t8[i], t8[i + 4]);
    float pmax = fmaxf(fmaxf(t4[0], t4[1]), fmaxf(t4[2], t4[3]));
    pmax = fmaxf(pmax, __shfl_xor(pmax, 32));

    // ---- T13 defer-max ----
    if (!__all(pmax <= m_r + 8.0f)) {
      const float mnew = fmaxf(m_r, pmax);
      const float corr = __expf(m_r - mnew);
      m_r = mnew;
      l_r *= corr;
      if (lane < 32) Sc[wv * 32 + ql] = corr;
      #pragma unroll
      for (int reg = 0; reg < 16; ++reg) {
        const float cr = Sc[wv * 32 + ((reg & 3) + 8 * (reg >> 2) + 4 * hi)];
        o0[reg] *= cr; o1[reg] *= cr;
      }
    }

    // ---- p = exp, rowsum ----
    float p[32];
    #pragma unroll
    for (int i = 0; i < 32; ++i) p[i] = __expf(lg[i] - m_r);
    float s16[16];
    #pragma unroll
    for (int i = 0; i < 16; ++i) s16[i] = p[i] + p[i + 16];
    float s8[8];
    #pragma unroll
    for (int i = 0; i < 8; ++i) s8[i] = s16[i] + s16[i + 8];
    float s4[4];
    #pragma unroll
    for (int i = 0; i < 4; ++i) s4[i] = s8[i] + s8[i + 4];
    float rs = (s4[0] + s4[1]) + (s4[2] + s4[3]);
    rs += __shfl_xor(rs, 32);
    l_r += rs;

    // ---- P -> bf16 A-fragments ----
    unsigned cc16[16];
    #pragma unroll
    for (int t = 0; t < 16; ++t) cc16[t] = pk2(p[2 * t], p[2 * t + 1]);
    short8 pa[4];
    #pragma unroll
    for (int ks = 0; ks < 4; ++ks) {
      unsigned snd0 = hi ? cc16[4 * ks]     : cc16[4 * ks + 2];
      unsigned snd1 = hi ? cc16[4 * ks + 1] : cc16[4 * ks + 3];
      unsigned e0 = __shfl_xor(snd0, 32);
      unsigned e1 = __shfl_xor(snd1, 32);
      uint4 dw;
      dw.x = hi ? e0 : cc16[4 * ks];
      dw.y = hi ? e1 : cc16[4 * ks + 1];
      dw.z = hi ? cc16[4 * ks + 2] : e0;
      dw.w = hi ? cc16[4 * ks + 3] : e1;
      pa[ks] = __builtin_bit_cast(short8, dw);
    }

    // ---- O += P V ----
    __builtin_amdgcn_s_setprio(1);
    #pragma unroll
    for (int nt = 0; nt < 2; ++nt) {
      const int d = nt * 32 + ql;
      const char* vb = (const char*)Vt[c] + d * 128;
      const int vswz = (((d & 7) ^ (d >> 3)) & 7) << 4;
      #pragma unroll
      for (int ks = 0; ks < 4; ++ks) {
        short8 bf = *(const short8*)(vb + ((ks * 32 + hi * 16) ^ vswz));
        if (nt == 0) o0 = __builtin_amdgcn_mfma_f32_32x32x16_bf16(pa[ks], bf, o0, 0, 0, 0);
        else         o1 = __builtin_amdgcn_mfma_f32_32x32x16_bf16(pa[ks], bf, o1, 0, 0, 0);
      }
    }
    __builtin_amdgcn_s_setprio(0);

    // ---- stage next tile; ONE barrier per tile ----
    if (kt < 15) {
      *(short8*)((char*)Ks[c ^ 1] + kwb0) = pack8(nk0, nk1);
      *(short8*)((char*)Ks[c ^ 1] + kwb1) = pack8(nk2, nk3);
      const float vr[4][4] = {{nr0.x, nr0.y, nr0.z, nr0.w}, {nr1.x, nr1.y, nr1.z, nr1.w},
                              {nr2.x, nr2.y, nr2.z, nr2.w}, {nr3.x, nr3.y, nr3.z, nr3.w}};
      #pragma unroll
      for (int dd = 0; dd < 4; ++dd) {
        uint2 w; w.x = pk2(vr[0][dd], vr[1][dd]); w.y = pk2(vr[2][dd], vr[3][dd]);
        *(uint2*)((char*)Vt[c ^ 1] + vwoff[dd]) = w;
      }
    }
    __syncthreads();
  }

  // ---- epilogue ----
  if (lane < 32) Sc[wv * 32 + ql] = l_r;
  #pragma unroll
  for (int reg = 0; reg < 16; ++reg) {
    const int qq = (reg & 3) + 8 * (reg >> 2) + 4 * hi;
    const float lv = Sc[wv * 32 + qq];
    const float inv = 1.0f / lv;
    float* op = O + ((size_t)(b * 1024 + qblk * 128 + wv * 32 + qq)) * 512 + h * 64 + ql;
    op[0]  = o0[reg] * inv;
    op[32] = o1[reg] * inv;
  }
}

extern "C" void kernel_launch(void* const* d_in, const int* in_sizes, int n_in,
                              void* d_out, int out_size, void* d_ws, size_t ws_size,
                              hipStream_t stream) {
  const float* Q   = (const float*)d_in[0];
  const float* K   = (const float*)d_in[1];
  const float* V   = (const float*)d_in[2];
  const float* WM  = (const float*)d_in[3];
  const float* TAU = (const float*)d_in[4];
  unsigned short* Wrm = (unsigned short*)d_ws;
  unsigned short* Wt  = (unsigned short*)((char*)d_ws + (1 << 21));
  float* out = (float*)d_out;

  w_softmax_kernel<<<dim3(1024), dim3(256), 0, stream>>>(WM, TAU, Wrm);
  w_transpose_kernel<<<dim3(256), dim3(256), 0, stream>>>(Wrm, Wt);
  attn_kernel<<<dim3(1024), dim3(256), 0, stream>>>(Q, K, V, Wt, out);
}

// Round 7
// 212.861 us; speedup vs baseline: 1.9329x; 1.9329x over previous
//
#include <hip/hip_runtime.h>

using short8 = __attribute__((ext_vector_type(8))) short;
using f32x16 = __attribute__((ext_vector_type(16))) float;
using bf16x2 = __attribute__((ext_vector_type(2))) __bf16;

__device__ __forceinline__ short b16(float f) {
  __bf16 h = (__bf16)f;
  return __builtin_bit_cast(short, h);
}
// packed pair -> v_cvt_pk_bf16_f32
__device__ __forceinline__ unsigned pk2(float lo, float hi) {
  bf16x2 t; t[0] = (__bf16)lo; t[1] = (__bf16)hi;
  return __builtin_bit_cast(unsigned, t);
}
__device__ __forceinline__ short8 pack8(const float4& a, const float4& b) {
  uint4 u;
  u.x = pk2(a.x, a.y); u.y = pk2(a.z, a.w);
  u.z = pk2(b.x, b.y); u.w = pk2(b.z, b.w);
  return __builtin_bit_cast(short8, u);
}
__device__ __forceinline__ float bflo(unsigned u) {
  return __builtin_bit_cast(float, u << 16);
}
__device__ __forceinline__ float bfhi(unsigned u) {
  return __builtin_bit_cast(float, u & 0xffff0000u);
}
__device__ __forceinline__ void glds16(const void* g, void* l) {
  __builtin_amdgcn_global_load_lds(
      (const __attribute__((address_space(1))) unsigned int*)g,
      (__attribute__((address_space(3))) unsigned int*)l, 16, 0, 0);
}

// Kernel 1: W' = softmax(weight_mat / softplus(tau)) * 0.125, bf16 row-major
__global__ __launch_bounds__(256) void w_softmax_kernel(
    const float* __restrict__ wm, const float* __restrict__ tau,
    unsigned short* __restrict__ wout) {
  const int row = blockIdx.x;
  const int tid = threadIdx.x;
  const float sp  = log1pf(__expf(tau[row]));
  const float inv = 1.0f / sp;
  const float4* src = (const float4*)(wm + (size_t)row * 1024);
  float4 v = src[tid];
  float v0 = v.x * inv, v1 = v.y * inv, v2 = v.z * inv, v3 = v.w * inv;
  float mx = fmaxf(fmaxf(v0, v1), fmaxf(v2, v3));
  #pragma unroll
  for (int m = 1; m < 64; m <<= 1) mx = fmaxf(mx, __shfl_xor(mx, m));
  __shared__ float red[8];
  const int wv = tid >> 6;
  if ((tid & 63) == 0) red[wv] = mx;
  __syncthreads();
  mx = fmaxf(fmaxf(red[0], red[1]), fmaxf(red[2], red[3]));
  float e0 = __expf(v0 - mx), e1 = __expf(v1 - mx);
  float e2 = __expf(v2 - mx), e3 = __expf(v3 - mx);
  float s = e0 + e1 + e2 + e3;
  #pragma unroll
  for (int m = 1; m < 64; m <<= 1) s += __shfl_xor(s, m);
  if ((tid & 63) == 0) red[4 + wv] = s;
  __syncthreads();
  s = red[4] + red[5] + red[6] + red[7];
  const float r = 0.125f / s;
  uint2 o; o.x = pk2(e0 * r, e1 * r); o.y = pk2(e2 * r, e3 * r);
  *(uint2*)(wout + (size_t)row * 1024 + tid * 4) = o;
}

// Kernel 2: Wt2[s/2][q] = packed pair (w[s][q], w[s+1][q]) bf16x2 in a dword.
__global__ __launch_bounds__(256) void w_transpose2_kernel(
    const unsigned short* __restrict__ win, unsigned* __restrict__ wt2) {
  __shared__ unsigned short tile[64][73];
  const int ti = blockIdx.x & 15;   // s-tile
  const int tj = blockIdx.x >> 4;   // q-tile
  const int t  = threadIdx.x;
  const int qa = t >> 2, sb = (t & 3) * 16;
  const unsigned short* src = win + (size_t)(tj * 64 + qa) * 1024 + ti * 64 + sb;
  short8 a0 = *(const short8*)(src);
  short8 a1 = *(const short8*)(src + 8);
  #pragma unroll
  for (int j = 0; j < 8; ++j) { tile[qa][sb + j] = a0[j]; tile[qa][sb + 8 + j] = a1[j]; }
  __syncthreads();
  const int s2l = t >> 3;           // 0..31 (pair index within tile)
  const int qc  = (t & 7) * 8;      // 0..56
  unsigned out[8];
  #pragma unroll
  for (int j = 0; j < 8; ++j)
    out[j] = (unsigned)tile[qc + j][2 * s2l] |
             ((unsigned)tile[qc + j][2 * s2l + 1] << 16);
  unsigned* dst = wt2 + (size_t)(ti * 32 + s2l) * 1024 + tj * 64 + qc;
  *(uint4*)(dst)     = *(uint4*)(&out[0]);
  *(uint4*)(dst + 4) = *(uint4*)(&out[4]);
}

// Kernel 3: prep K,V -> bf16, pre-swizzled (K) / pre-transposed+swizzled (V)
// 8KB tiles laid out so a LINEAR global_load_lds reproduces the exact LDS
// image the attention kernel's verified fragment reads expect.
// block = (bh*16 + kt), 256 threads.
__global__ __launch_bounds__(256) void prep_kv_kernel(
    const float* __restrict__ K, const float* __restrict__ V,
    unsigned short* __restrict__ KP, unsigned short* __restrict__ VP) {
  const int bid = blockIdx.x;
  const int kt = bid & 15, bh = bid >> 4;
  const int b = bh >> 3, h = bh & 7;
  const int t = threadIdx.x;
  const int s = t >> 2, e0 = (t & 3) * 16;

  // K: short(s,e) at byte s*128 + ((2e) ^ ((s&7)<<4))
  {
    const float* kp = K + ((size_t)(b * 1024 + kt * 64 + s)) * 512 + h * 64 + e0;
    float4 x0 = *(const float4*)(kp);
    float4 x1 = *(const float4*)(kp + 4);
    float4 x2 = *(const float4*)(kp + 8);
    float4 x3 = *(const float4*)(kp + 12);
    char* kdst = (char*)KP + ((size_t)bh * 16 + kt) * 8192;
    const int sw = (s & 7) << 4;
    *(short8*)(kdst + s * 128 + ((2 * e0) ^ sw))      = pack8(x0, x1);
    *(short8*)(kdst + s * 128 + ((2 * e0 + 16) ^ sw)) = pack8(x2, x3);
  }

  // V: transpose via LDS; short(d,s) at byte d*128 + ((2s) ^ vz(d))
  __shared__ float Vf[64][65];
  {
    const float* vp = V + ((size_t)(b * 1024 + kt * 64 + s)) * 512 + h * 64 + e0;
    float4 y0 = *(const float4*)(vp);
    float4 y1 = *(const float4*)(vp + 4);
    float4 y2 = *(const float4*)(vp + 8);
    float4 y3 = *(const float4*)(vp + 12);
    #pragma unroll
    for (int j = 0; j < 4; ++j) {
      Vf[s][e0 + j]      = ((const float*)&y0)[j];
      Vf[s][e0 + 4 + j]  = ((const float*)&y1)[j];
      Vf[s][e0 + 8 + j]  = ((const float*)&y2)[j];
      Vf[s][e0 + 12 + j] = ((const float*)&y3)[j];
    }
  }
  __syncthreads();
  {
    const int d = t >> 2, sb = (t & 3) * 16;
    float4 v0, v1, v2, v3;
    #pragma unroll
    for (int j = 0; j < 4; ++j) {
      ((float*)&v0)[j] = Vf[sb + j][d];
      ((float*)&v1)[j] = Vf[sb + 4 + j][d];
      ((float*)&v2)[j] = Vf[sb + 8 + j][d];
      ((float*)&v3)[j] = Vf[sb + 12 + j][d];
    }
    char* vdst = (char*)VP + ((size_t)bh * 16 + kt) * 8192;
    const int vz = (((d & 7) ^ (d >> 3)) & 7) << 4;
    *(short8*)(vdst + d * 128 + ((2 * sb) ^ vz))      = pack8(v0, v1);
    *(short8*)(vdst + d * 128 + ((2 * sb + 16) ^ vz)) = pack8(v2, v3);
  }
}

// ---- shared core of the attention kernel (macro-free, duplicated) ----

// Kernel 4a: FAST path — stage prepped bf16 tiles via global_load_lds.
__global__ __launch_bounds__(256, 3) void attn_fast_kernel(
    const float* __restrict__ Q, const unsigned short* __restrict__ KP,
    const unsigned short* __restrict__ VP, const unsigned* __restrict__ Wt2,
    float* __restrict__ O) {
  const int orig = blockIdx.x;                 // 1024 blocks
  const int xcd  = orig & 7, slot = orig >> 3;
  const int bh   = xcd * 16 + (slot >> 3);
  const int qblk = slot & 7;
  const int b = bh >> 3, h = bh & 7;

  const int tid = threadIdx.x, wv = tid >> 6, lane = tid & 63;
  const int ql = lane & 31, hi = lane >> 5;
  const int qg = qblk * 128 + wv * 32 + ql;

  __shared__ alignas(16) short Ks[2][4096];
  __shared__ alignas(16) short Vt[2][4096];
  __shared__ float Sc[128];

  // Q B-fragments
  const float* qrow = Q + ((size_t)(b * 1024 + qg)) * 512 + h * 64;
  short8 qb[4];
  #pragma unroll
  for (int es = 0; es < 4; ++es) {
    float4 f0 = *(const float4*)(qrow + es * 16 + hi * 8);
    float4 f1 = *(const float4*)(qrow + es * 16 + hi * 8 + 4);
    qb[es] = pack8(f0, f1);
  }

  const char* kpb = (const char*)KP + (size_t)bh * 131072;
  const char* vpb = (const char*)VP + (size_t)bh * 131072;
  const int goff = tid * 16;
  const int loff = wv * 1024;   // wave-uniform LDS base offset

  // prologue: stage tile 0 into buffer 0
  {
    const char* ks = kpb;
    const char* vs = vpb;
    glds16(ks + goff,        (char*)Ks[0] + loff);
    glds16(ks + 4096 + goff, (char*)Ks[0] + 4096 + loff);
    glds16(vs + goff,        (char*)Vt[0] + loff);
    glds16(vs + 4096 + goff, (char*)Vt[0] + 4096 + loff);
  }
  __syncthreads();

  f32x16 o0, o1;
  #pragma unroll
  for (int i = 0; i < 16; ++i) { o0[i] = 0.f; o1[i] = 0.f; }
  float m_r = -INFINITY, l_r = 0.f;

  const unsigned* wcol = Wt2 + qg;

  #pragma unroll 1
  for (int kt = 0; kt < 16; ++kt) {
    const int c = kt & 1;

    // ---- stage next tile into buf c^1 (no registers held) ----
    if (kt < 15) {
      const char* ks = kpb + (kt + 1) * 8192;
      const char* vs = vpb + (kt + 1) * 8192;
      glds16(ks + goff,        (char*)Ks[c ^ 1] + loff);
      glds16(ks + 4096 + goff, (char*)Ks[c ^ 1] + 4096 + loff);
      glds16(vs + goff,        (char*)Vt[c ^ 1] + loff);
      glds16(vs + 4096 + goff, (char*)Vt[c ^ 1] + 4096 + loff);
    }
    __builtin_amdgcn_sched_barrier(0);

    // ---- this tile's w: 16 packed dword loads ----
    unsigned wu2[16];
    #pragma unroll
    for (int st = 0; st < 2; ++st)
      #pragma unroll
      for (int rg = 0; rg < 4; ++rg)
        #pragma unroll
        for (int p = 0; p < 2; ++p)
          wu2[st * 8 + rg * 2 + p] =
              wcol[(size_t)(kt * 32 + st * 16 + rg * 4 + 2 * hi + p) * 1024];

    // ---- S^T = mfma(K, Q) ----
    f32x16 sa0, sa1;
    #pragma unroll
    for (int i = 0; i < 16; ++i) { sa0[i] = 0.f; sa1[i] = 0.f; }
    {
      const int sr0 = ql, sr1 = 32 + ql;
      const char* kb0 = (const char*)Ks[c] + sr0 * 128;
      const char* kb1 = (const char*)Ks[c] + sr1 * 128;
      const int sz0 = (sr0 & 7) << 4, sz1 = (sr1 & 7) << 4;
      __builtin_amdgcn_s_setprio(1);
      #pragma unroll
      for (int es = 0; es < 4; ++es) {
        short8 ka0 = *(const short8*)(kb0 + ((es * 32 + hi * 16) ^ sz0));
        short8 ka1 = *(const short8*)(kb1 + ((es * 32 + hi * 16) ^ sz1));
        sa0 = __builtin_amdgcn_mfma_f32_32x32x16_bf16(ka0, qb[es], sa0, 0, 0, 0);
        sa1 = __builtin_amdgcn_mfma_f32_32x32x16_bf16(ka1, qb[es], sa1, 0, 0, 0);
      }
      __builtin_amdgcn_s_setprio(0);
    }

    // ---- logits (paired w unpack: lshl / and only) ----
    float lg[32];
    #pragma unroll
    for (int st = 0; st < 2; ++st)
      #pragma unroll
      for (int rg = 0; rg < 4; ++rg) {
        const unsigned wlo = wu2[st * 8 + rg * 2 + 0];
        const unsigned whi = wu2[st * 8 + rg * 2 + 1];
        const int rb = st * 16 + rg * 4;
        const float* sv = st ? (const float*)&sa1 : (const float*)&sa0;
        lg[rb + 0] = sv[rg * 4 + 0] * bflo(wlo);
        lg[rb + 1] = sv[rg * 4 + 1] * bfhi(wlo);
        lg[rb + 2] = sv[rg * 4 + 2] * bflo(whi);
        lg[rb + 3] = sv[rg * 4 + 3] * bfhi(whi);
      }

    // ---- max tree + one cross-half shfl ----
    float t16[16];
    #pragma unroll
    for (int i = 0; i < 16; ++i) t16[i] = fmaxf(lg[i], lg[i + 16]);
    float t8[8];
    #pragma unroll
    for (int i = 0; i < 8; ++i) t8[i] = fmaxf(t16[i], t16[i + 8]);
    float t4[4];
    #pragma unroll
    for (int i = 0; i < 4; ++i) t4[i] = fmaxf(t8[i], t8[i + 4]);
    float pmax = fmaxf(fmaxf(t4[0], t4[1]), fmaxf(t4[2], t4[3]));
    pmax = fmaxf(pmax, __shfl_xor(pmax, 32));

    // ---- T13 defer-max ----
    if (!__all(pmax <= m_r + 8.0f)) {
      const float mnew = fmaxf(m_r, pmax);
      const float corr = __expf(m_r - mnew);
      m_r = mnew;
      l_r *= corr;
      if (lane < 32) Sc[wv * 32 + ql] = corr;
      #pragma unroll
      for (int reg = 0; reg < 16; ++reg) {
        const float cr = Sc[wv * 32 + ((reg & 3) + 8 * (reg >> 2) + 4 * hi)];
        o0[reg] *= cr; o1[reg] *= cr;
      }
    }

    // ---- p = exp, rowsum ----
    float p[32];
    #pragma unroll
    for (int i = 0; i < 32; ++i) p[i] = __expf(lg[i] - m_r);
    float s16[16];
    #pragma unroll
    for (int i = 0; i < 16; ++i) s16[i] = p[i] + p[i + 16];
    float s8[8];
    #pragma unroll
    for (int i = 0; i < 8; ++i) s8[i] = s16[i] + s16[i + 8];
    float s4[4];
    #pragma unroll
    for (int i = 0; i < 4; ++i) s4[i] = s8[i] + s8[i + 4];
    float rs = (s4[0] + s4[1]) + (s4[2] + s4[3]);
    rs += __shfl_xor(rs, 32);
    l_r += rs;

    // ---- P -> bf16 A-fragments ----
    unsigned cc16[16];
    #pragma unroll
    for (int t = 0; t < 16; ++t) cc16[t] = pk2(p[2 * t], p[2 * t + 1]);
    short8 pa[4];
    #pragma unroll
    for (int ks = 0; ks < 4; ++ks) {
      unsigned snd0 = hi ? cc16[4 * ks]     : cc16[4 * ks + 2];
      unsigned snd1 = hi ? cc16[4 * ks + 1] : cc16[4 * ks + 3];
      unsigned e0 = __shfl_xor(snd0, 32);
      unsigned e1 = __shfl_xor(snd1, 32);
      uint4 dw;
      dw.x = hi ? e0 : cc16[4 * ks];
      dw.y = hi ? e1 : cc16[4 * ks + 1];
      dw.z = hi ? cc16[4 * ks + 2] : e0;
      dw.w = hi ? cc16[4 * ks + 3] : e1;
      pa[ks] = __builtin_bit_cast(short8, dw);
    }

    // ---- O += P V ----
    __builtin_amdgcn_s_setprio(1);
    #pragma unroll
    for (int nt = 0; nt < 2; ++nt) {
      const int d = nt * 32 + ql;
      const char* vb = (const char*)Vt[c] + d * 128;
      const int vswz = (((d & 7) ^ (d >> 3)) & 7) << 4;
      #pragma unroll
      for (int ks = 0; ks < 4; ++ks) {
        short8 bf = *(const short8*)(vb + ((ks * 32 + hi * 16) ^ vswz));
        if (nt == 0) o0 = __builtin_amdgcn_mfma_f32_32x32x16_bf16(pa[ks], bf, o0, 0, 0, 0);
        else         o1 = __builtin_amdgcn_mfma_f32_32x32x16_bf16(pa[ks], bf, o1, 0, 0, 0);
      }
    }
    __builtin_amdgcn_s_setprio(0);

    __syncthreads();   // drains glds (vmcnt0) + all reads of buf c done
  }

  // ---- epilogue ----
  if (lane < 32) Sc[wv * 32 + ql] = l_r;
  #pragma unroll
  for (int reg = 0; reg < 16; ++reg) {
    const int qq = (reg & 3) + 8 * (reg >> 2) + 4 * hi;
    const float lv = Sc[wv * 32 + qq];
    const float inv = 1.0f / lv;
    float* op = O + ((size_t)(b * 1024 + qblk * 128 + wv * 32 + qq)) * 512 + h * 64 + ql;
    op[0]  = o0[reg] * inv;
    op[32] = o1[reg] * inv;
  }
}

// Kernel 4b: FALLBACK (R5 structure, reg staging; only w-load path updated).
__global__ __launch_bounds__(256, 2) void attn_reg_kernel(
    const float* __restrict__ Q, const float* __restrict__ K,
    const float* __restrict__ V, const unsigned* __restrict__ Wt2,
    float* __restrict__ O) {
  const int orig = blockIdx.x;
  const int xcd  = orig & 7, slot = orig >> 3;
  const int bh   = xcd * 16 + (slot >> 3);
  const int qblk = slot & 7;
  const int b = bh >> 3, h = bh & 7;

  const int tid = threadIdx.x, wv = tid >> 6, lane = tid & 63;
  const int ql = lane & 31, hi = lane >> 5;
  const int qg = qblk * 128 + wv * 32 + ql;

  __shared__ alignas(16) short Ks[2][4096];
  __shared__ alignas(16) short Vt[2][4096];
  __shared__ float Sc[128];

  const float* qrow = Q + ((size_t)(b * 1024 + qg)) * 512 + h * 64;
  short8 qb[4];
  #pragma unroll
  for (int es = 0; es < 4; ++es) {
    float4 f0 = *(const float4*)(qrow + es * 16 + hi * 8);
    float4 f1 = *(const float4*)(qrow + es * 16 + hi * 8 + 4);
    qb[es] = pack8(f0, f1);
  }

  const int srow = tid >> 2;
  const int cgrp = (tid & 3) * 16;
  const float* kp = K + ((size_t)(b * 1024 + srow)) * 512 + h * 64 + cgrp;
  const int kswz = (srow & 7) << 4;
  const int kwb0 = srow * 128 + ((cgrp * 2) ^ kswz);
  const int kwb1 = srow * 128 + ((cgrp * 2 + 16) ^ kswz);

  const int vs0 = (tid >> 4) * 4;
  const int vd0 = (tid & 15) * 4;
  const float* vp = V + ((size_t)(b * 1024 + vs0)) * 512 + h * 64 + vd0;
  int vwoff[4];
  #pragma unroll
  for (int dd = 0; dd < 4; ++dd) {
    const int d = vd0 + dd;
    vwoff[dd] = d * 128 + ((vs0 * 2) ^ ((((d & 7) ^ (d >> 3)) & 7) << 4));
  }

  {
    float4 a0 = *(const float4*)(kp);
    float4 a1 = *(const float4*)(kp + 4);
    float4 a2 = *(const float4*)(kp + 8);
    float4 a3 = *(const float4*)(kp + 12);
    float4 r0 = *(const float4*)(vp);
    float4 r1 = *(const float4*)(vp + 512);
    float4 r2 = *(const float4*)(vp + 1024);
    float4 r3 = *(const float4*)(vp + 1536);
    *(short8*)((char*)Ks[0] + kwb0) = pack8(a0, a1);
    *(short8*)((char*)Ks[0] + kwb1) = pack8(a2, a3);
    const float vr[4][4] = {{r0.x, r0.y, r0.z, r0.w}, {r1.x, r1.y, r1.z, r1.w},
                            {r2.x, r2.y, r2.z, r2.w}, {r3.x, r3.y, r3.z, r3.w}};
    #pragma unroll
    for (int dd = 0; dd < 4; ++dd) {
      uint2 w; w.x = pk2(vr[0][dd], vr[1][dd]); w.y = pk2(vr[2][dd], vr[3][dd]);
      *(uint2*)((char*)Vt[0] + vwoff[dd]) = w;
    }
  }
  __syncthreads();

  f32x16 o0, o1;
  #pragma unroll
  for (int i = 0; i < 16; ++i) { o0[i] = 0.f; o1[i] = 0.f; }
  float m_r = -INFINITY, l_r = 0.f;
  const unsigned* wcol = Wt2 + qg;

  #pragma unroll 1
  for (int kt = 0; kt < 16; ++kt) {
    const int c = kt & 1;

    float4 nk0, nk1, nk2, nk3, nr0, nr1, nr2, nr3;
    if (kt < 15) {
      const size_t soff = (size_t)((kt + 1) * 64) * 512;
      nk0 = *(const float4*)(kp + soff);        nk1 = *(const float4*)(kp + soff + 4);
      nk2 = *(const float4*)(kp + soff + 8);    nk3 = *(const float4*)(kp + soff + 12);
      nr0 = *(const float4*)(vp + soff);        nr1 = *(const float4*)(vp + soff + 512);
      nr2 = *(const float4*)(vp + soff + 1024); nr3 = *(const float4*)(vp + soff + 1536);
    }

    unsigned wu2[16];
    #pragma unroll
    for (int st = 0; st < 2; ++st)
      #pragma unroll
      for (int rg = 0; rg < 4; ++rg)
        #pragma unroll
        for (int p = 0; p < 2; ++p)
          wu2[st * 8 + rg * 2 + p] =
              wcol[(size_t)(kt * 32 + st * 16 + rg * 4 + 2 * hi + p) * 1024];

    f32x16 sa0, sa1;
    #pragma unroll
    for (int i = 0; i < 16; ++i) { sa0[i] = 0.f; sa1[i] = 0.f; }
    {
      const int sr0 = ql, sr1 = 32 + ql;
      const char* kb0 = (const char*)Ks[c] + sr0 * 128;
      const char* kb1 = (const char*)Ks[c] + sr1 * 128;
      const int sz0 = (sr0 & 7) << 4, sz1 = (sr1 & 7) << 4;
      __builtin_amdgcn_s_setprio(1);
      #pragma unroll
      for (int es = 0; es < 4; ++es) {
        short8 ka0 = *(const short8*)(kb0 + ((es * 32 + hi * 16) ^ sz0));
        short8 ka1 = *(const short8*)(kb1 + ((es * 32 + hi * 16) ^ sz1));
        sa0 = __builtin_amdgcn_mfma_f32_32x32x16_bf16(ka0, qb[es], sa0, 0, 0, 0);
        sa1 = __builtin_amdgcn_mfma_f32_32x32x16_bf16(ka1, qb[es], sa1, 0, 0, 0);
      }
      __builtin_amdgcn_s_setprio(0);
    }

    float lg[32];
    #pragma unroll
    for (int st = 0; st < 2; ++st)
      #pragma unroll
      for (int rg = 0; rg < 4; ++rg) {
        const unsigned wlo = wu2[st * 8 + rg * 2 + 0];
        const unsigned whi = wu2[st * 8 + rg * 2 + 1];
        const int rb = st * 16 + rg * 4;
        const float* sv = st ? (const float*)&sa1 : (const float*)&sa0;
        lg[rb + 0] = sv[rg * 4 + 0] * bflo(wlo);
        lg[rb + 1] = sv[rg * 4 + 1] * bfhi(wlo);
        lg[rb + 2] = sv[rg * 4 + 2] * bflo(whi);
        lg[rb + 3] = sv[rg * 4 + 3] * bfhi(whi);
      }

    float t16[16];
    #pragma unroll
    for (int i = 0; i < 16; ++i) t16[i] = fmaxf(lg[i], lg[i + 16]);
    float t8[8];
    #pragma unroll
    for (int i = 0; i < 8; ++i) t8[i] = fmaxf(t16[i], t16[i + 8]);
    float t4[4];
    #pragma unroll
    for (int i = 0; i < 4; ++i) t4[i] = fmaxf(t8[i], t8[i + 4]);
    float pmax = fmaxf(fmaxf(t4[0], t4[1]), fmaxf(t4[2], t4[3]));
    pmax = fmaxf(pmax, __shfl_xor(pmax, 32));

    if (!__all(pmax <= m_r + 8.0f)) {
      const float mnew = fmaxf(m_r, pmax);
      const float corr = __expf(m_r - mnew);
      m_r = mnew;
      l_r *= corr;
      if (lane < 32) Sc[wv * 32 + ql] = corr;
      #pragma unroll
      for (int reg = 0; reg < 16; ++reg) {
        const float cr = Sc[wv * 32 + ((reg & 3) + 8 * (reg >> 2) + 4 * hi)];
        o0[reg] *= cr; o1[reg] *= cr;
      }
    }

    float p[32];
    #pragma unroll
    for (int i = 0; i < 32; ++i) p[i] = __expf(lg[i] - m_r);
    float s16[16];
    #pragma unroll
    for (int i = 0; i < 16; ++i) s16[i] = p[i] + p[i + 16];
    float s8[8];
    #pragma unroll
    for (int i = 0; i < 8; ++i) s8[i] = s16[i] + s16[i + 8];
    float s4[4];
    #pragma unroll
    for (int i = 0; i < 4; ++i) s4[i] = s8[i] + s8[i + 4];
    float rs = (s4[0] + s4[1]) + (s4[2] + s4[3]);
    rs += __shfl_xor(rs, 32);
    l_r += rs;

    unsigned cc16[16];
    #pragma unroll
    for (int t = 0; t < 16; ++t) cc16[t] = pk2(p[2 * t], p[2 * t + 1]);
    short8 pa[4];
    #pragma unroll
    for (int ks = 0; ks < 4; ++ks) {
      unsigned snd0 = hi ? cc16[4 * ks]     : cc16[4 * ks + 2];
      unsigned snd1 = hi ? cc16[4 * ks + 1] : cc16[4 * ks + 3];
      unsigned e0 = __shfl_xor(snd0, 32);
      unsigned e1 = __shfl_xor(snd1, 32);
      uint4 dw;
      dw.x = hi ? e0 : cc16[4 * ks];
      dw.y = hi ? e1 : cc16[4 * ks + 1];
      dw.z = hi ? cc16[4 * ks + 2] : e0;
      dw.w = hi ? cc16[4 * ks + 3] : e1;
      pa[ks] = __builtin_bit_cast(short8, dw);
    }

    __builtin_amdgcn_s_setprio(1);
    #pragma unroll
    for (int nt = 0; nt < 2; ++nt) {
      const int d = nt * 32 + ql;
      const char* vb = (const char*)Vt[c] + d * 128;
      const int vswz = (((d & 7) ^ (d >> 3)) & 7) << 4;
      #pragma unroll
      for (int ks = 0; ks < 4; ++ks) {
        short8 bf = *(const short8*)(vb + ((ks * 32 + hi * 16) ^ vswz));
        if (nt == 0) o0 = __builtin_amdgcn_mfma_f32_32x32x16_bf16(pa[ks], bf, o0, 0, 0, 0);
        else         o1 = __builtin_amdgcn_mfma_f32_32x32x16_bf16(pa[ks], bf, o1, 0, 0, 0);
      }
    }
    __builtin_amdgcn_s_setprio(0);

    if (kt < 15) {
      *(short8*)((char*)Ks[c ^ 1] + kwb0) = pack8(nk0, nk1);
      *(short8*)((char*)Ks[c ^ 1] + kwb1) = pack8(nk2, nk3);
      const float vr[4][4] = {{nr0.x, nr0.y, nr0.z, nr0.w}, {nr1.x, nr1.y, nr1.z, nr1.w},
                              {nr2.x, nr2.y, nr2.z, nr2.w}, {nr3.x, nr3.y, nr3.z, nr3.w}};
      #pragma unroll
      for (int dd = 0; dd < 4; ++dd) {
        uint2 w; w.x = pk2(vr[0][dd], vr[1][dd]); w.y = pk2(vr[2][dd], vr[3][dd]);
        *(uint2*)((char*)Vt[c ^ 1] + vwoff[dd]) = w;
      }
    }
    __syncthreads();
  }

  if (lane < 32) Sc[wv * 32 + ql] = l_r;
  #pragma unroll
  for (int reg = 0; reg < 16; ++reg) {
    const int qq = (reg & 3) + 8 * (reg >> 2) + 4 * hi;
    const float lv = Sc[wv * 32 + qq];
    const float inv = 1.0f / lv;
    float* op = O + ((size_t)(b * 1024 + qblk * 128 + wv * 32 + qq)) * 512 + h * 64 + ql;
    op[0]  = o0[reg] * inv;
    op[32] = o1[reg] * inv;
  }
}

extern "C" void kernel_launch(void* const* d_in, const int* in_sizes, int n_in,
                              void* d_out, int out_size, void* d_ws, size_t ws_size,
                              hipStream_t stream) {
  const float* Q   = (const float*)d_in[0];
  const float* K   = (const float*)d_in[1];
  const float* V   = (const float*)d_in[2];
  const float* WM  = (const float*)d_in[3];
  const float* TAU = (const float*)d_in[4];
  float* out = (float*)d_out;

  unsigned short* Wrm = (unsigned short*)d_ws;                       // 2 MB
  unsigned*       Wt2 = (unsigned*)((char*)d_ws + (2ull << 20));     // 4 MB
  unsigned short* KP  = (unsigned short*)((char*)d_ws + (6ull << 20));  // 16 MB
  unsigned short* VP  = (unsigned short*)((char*)d_ws + (22ull << 20)); // 16 MB
  const size_t NEED = 38ull << 20;

  w_softmax_kernel<<<dim3(1024), dim3(256), 0, stream>>>(WM, TAU, Wrm);
  w_transpose2_kernel<<<dim3(256), dim3(256), 0, stream>>>(Wrm, Wt2);
  if (ws_size >= NEED) {
    prep_kv_kernel<<<dim3(2048), dim3(256), 0, stream>>>(K, V, KP, VP);
    attn_fast_kernel<<<dim3(1024), dim3(256), 0, stream>>>(Q, KP, VP, Wt2, out);
  } else {
    attn_reg_kernel<<<dim3(1024), dim3(256), 0, stream>>>(Q, K, V, Wt2, out);
  }
}

// Round 8
// 206.104 us; speedup vs baseline: 1.9963x; 1.0328x over previous
//
#include <hip/hip_runtime.h>

using short8 = __attribute__((ext_vector_type(8))) short;
using f32x16 = __attribute__((ext_vector_type(16))) float;
using bf16x2 = __attribute__((ext_vector_type(2))) __bf16;

__device__ __forceinline__ unsigned pk2(float lo, float hi) {
  bf16x2 t; t[0] = (__bf16)lo; t[1] = (__bf16)hi;
  return __builtin_bit_cast(unsigned, t);
}
__device__ __forceinline__ short8 pack8(const float4& a, const float4& b) {
  uint4 u;
  u.x = pk2(a.x, a.y); u.y = pk2(a.z, a.w);
  u.z = pk2(b.x, b.y); u.w = pk2(b.z, b.w);
  return __builtin_bit_cast(short8, u);
}
__device__ __forceinline__ float bflo(unsigned u) {
  return __builtin_bit_cast(float, u << 16);
}
__device__ __forceinline__ float bfhi(unsigned u) {
  return __builtin_bit_cast(float, u & 0xffff0000u);
}
#if __has_builtin(__builtin_amdgcn_exp2f)
__device__ __forceinline__ float ex2(float x) { return __builtin_amdgcn_exp2f(x); }
#else
__device__ __forceinline__ float ex2(float x) { return exp2f(x); }
#endif
__device__ __forceinline__ void glds16(const void* g, void* l) {
  __builtin_amdgcn_global_load_lds(
      (const __attribute__((address_space(1))) unsigned int*)g,
      (__attribute__((address_space(3))) unsigned int*)l, 16, 0, 0);
}

// Kernel 1 (fused): bid<2048 -> prep K/V bf16 pre-swizzled tiles;
// bid>=2048 (64 blocks) -> W softmax + transpose, writing Wt2 directly.
// W' = softmax(wm / softplus(tau)) * 0.125 * log2(e)   [log2-domain logits]
__global__ __launch_bounds__(256) void prep_fused_kernel(
    const float* __restrict__ K, const float* __restrict__ V,
    const float* __restrict__ WM, const float* __restrict__ TAU,
    unsigned short* __restrict__ KP, unsigned short* __restrict__ VP,
    unsigned* __restrict__ Wt2) {
  __shared__ float Vf[64][65];
  const int bid = blockIdx.x;
  const int t = threadIdx.x;
  if (bid < 2048) {
    const int kt = bid & 15, bh = bid >> 4;
    const int b = bh >> 3, h = bh & 7;
    const int s = t >> 2, e0 = (t & 3) * 16;
    // K: short(s,e) at byte s*128 + ((2e) ^ ((s&7)<<4))
    {
      const float* kp = K + ((size_t)(b * 1024 + kt * 64 + s)) * 512 + h * 64 + e0;
      float4 x0 = *(const float4*)(kp);
      float4 x1 = *(const float4*)(kp + 4);
      float4 x2 = *(const float4*)(kp + 8);
      float4 x3 = *(const float4*)(kp + 12);
      char* kdst = (char*)KP + ((size_t)bh * 16 + kt) * 8192;
      const int sw = (s & 7) << 4;
      *(short8*)(kdst + s * 128 + ((2 * e0) ^ sw))      = pack8(x0, x1);
      *(short8*)(kdst + s * 128 + ((2 * e0 + 16) ^ sw)) = pack8(x2, x3);
    }
    // V: transpose via LDS; short(d,s) at byte d*128 + ((2s) ^ vz(d))
    {
      const float* vp = V + ((size_t)(b * 1024 + kt * 64 + s)) * 512 + h * 64 + e0;
      float4 y0 = *(const float4*)(vp);
      float4 y1 = *(const float4*)(vp + 4);
      float4 y2 = *(const float4*)(vp + 8);
      float4 y3 = *(const float4*)(vp + 12);
      #pragma unroll
      for (int j = 0; j < 4; ++j) {
        Vf[s][e0 + j]      = ((const float*)&y0)[j];
        Vf[s][e0 + 4 + j]  = ((const float*)&y1)[j];
        Vf[s][e0 + 8 + j]  = ((const float*)&y2)[j];
        Vf[s][e0 + 12 + j] = ((const float*)&y3)[j];
      }
    }
    __syncthreads();
    {
      const int d = t >> 2, sb = (t & 3) * 16;
      float4 v0, v1, v2, v3;
      #pragma unroll
      for (int j = 0; j < 4; ++j) {
        ((float*)&v0)[j] = Vf[sb + j][d];
        ((float*)&v1)[j] = Vf[sb + 4 + j][d];
        ((float*)&v2)[j] = Vf[sb + 8 + j][d];
        ((float*)&v3)[j] = Vf[sb + 12 + j][d];
      }
      char* vdst = (char*)VP + ((size_t)bh * 16 + kt) * 8192;
      const int vz = (((d & 7) ^ (d >> 3)) & 7) << 4;
      *(short8*)(vdst + d * 128 + ((2 * sb) ^ vz))      = pack8(v0, v1);
      *(short8*)(vdst + d * 128 + ((2 * sb + 16) ^ vz)) = pack8(v2, v3);
    }
  } else {
    // W path: 64 blocks x 16 rows; 16 threads per row, 64 elems each
    // (interleaved: elem(i,j) -> col lc*4 + i*64 + j, coalesced loads)
    const int wb = bid - 2048;
    const int row = wb * 16 + (t >> 4);
    const int lc = t & 15;
    const float sp  = log1pf(__expf(TAU[row]));
    const float inv = 1.0f / sp;
    const float* src = WM + (size_t)row * 1024 + lc * 4;
    float4 v[16];
    #pragma unroll
    for (int i = 0; i < 16; ++i) v[i] = *(const float4*)(src + i * 64);
    float mx = -INFINITY;
    #pragma unroll
    for (int i = 0; i < 16; ++i) {
      v[i].x *= inv; v[i].y *= inv; v[i].z *= inv; v[i].w *= inv;
      mx = fmaxf(mx, fmaxf(fmaxf(v[i].x, v[i].y), fmaxf(v[i].z, v[i].w)));
    }
    #pragma unroll
    for (int m = 1; m < 16; m <<= 1) mx = fmaxf(mx, __shfl_xor(mx, m));
    float s = 0.f;
    #pragma unroll
    for (int i = 0; i < 16; ++i) {
      v[i].x = __expf(v[i].x - mx); v[i].y = __expf(v[i].y - mx);
      v[i].z = __expf(v[i].z - mx); v[i].w = __expf(v[i].w - mx);
      s += (v[i].x + v[i].y) + (v[i].z + v[i].w);
    }
    #pragma unroll
    for (int m = 1; m < 16; m <<= 1) s += __shfl_xor(s, m);
    const float r = 0.125f * 1.44269504f / s;   // fold 1/sqrt(64) and log2(e)
    unsigned* dst = Wt2 + row;                  // column q = row
    #pragma unroll
    for (int i = 0; i < 16; ++i) {
      const int s2 = lc * 2 + i * 32;
      dst[(size_t)s2 * 1024]       = pk2(v[i].x * r, v[i].y * r);
      dst[(size_t)(s2 + 1) * 1024] = pk2(v[i].z * r, v[i].w * r);
    }
  }
}

// Kernel 2: 32x32 swapped-QK flash attention, log2-domain softmax.
// 4 waves x 32 q-rows = 128 q/block; 4 blocks/CU -> whole grid resident.
__global__ __launch_bounds__(256, 4) void attn_fast_kernel(
    const float* __restrict__ Q, const unsigned short* __restrict__ KP,
    const unsigned short* __restrict__ VP, const unsigned* __restrict__ Wt2,
    float* __restrict__ O) {
  const int orig = blockIdx.x;                 // 1024 blocks
  const int xcd  = orig & 7, slot = orig >> 3;
  const int bh   = xcd * 16 + (slot >> 3);
  const int qblk = slot & 7;
  const int b = bh >> 3, h = bh & 7;

  const int tid = threadIdx.x, wv = tid >> 6, lane = tid & 63;
  const int ql = lane & 31, hi = lane >> 5;
  const int qg = qblk * 128 + wv * 32 + ql;

  __shared__ alignas(16) short Ks[2][4096];
  __shared__ alignas(16) short Vt[2][4096];
  __shared__ float Sc[128];

  // Q B-fragments: lane ql = q, k = es*16 + hi*8 + j
  const float* qrow = Q + ((size_t)(b * 1024 + qg)) * 512 + h * 64;
  short8 qb[4];
  #pragma unroll
  for (int es = 0; es < 4; ++es) {
    float4 f0 = *(const float4*)(qrow + es * 16 + hi * 8);
    float4 f1 = *(const float4*)(qrow + es * 16 + hi * 8 + 4);
    qb[es] = pack8(f0, f1);
  }

  const char* kpb = (const char*)KP + (size_t)bh * 131072;
  const char* vpb = (const char*)VP + (size_t)bh * 131072;
  const int goff = tid * 16;
  const int loff = wv * 1024;   // wave-uniform LDS base

  {   // prologue: stage tile 0
    glds16(kpb + goff,        (char*)Ks[0] + loff);
    glds16(kpb + 4096 + goff, (char*)Ks[0] + 4096 + loff);
    glds16(vpb + goff,        (char*)Vt[0] + loff);
    glds16(vpb + 4096 + goff, (char*)Vt[0] + 4096 + loff);
  }
  __syncthreads();

  f32x16 o0, o1;
  #pragma unroll
  for (int i = 0; i < 16; ++i) { o0[i] = 0.f; o1[i] = 0.f; }
  float m_r = -INFINITY, l_r = 0.f;

  const unsigned* wcol = Wt2 + qg;

  #pragma unroll 1
  for (int kt = 0; kt < 16; ++kt) {
    const int c = kt & 1;

    if (kt < 15) {   // stage next tile (no registers held)
      const char* ks = kpb + (kt + 1) * 8192;
      const char* vs = vpb + (kt + 1) * 8192;
      glds16(ks + goff,        (char*)Ks[c ^ 1] + loff);
      glds16(ks + 4096 + goff, (char*)Ks[c ^ 1] + 4096 + loff);
      glds16(vs + goff,        (char*)Vt[c ^ 1] + loff);
      glds16(vs + 4096 + goff, (char*)Vt[c ^ 1] + 4096 + loff);
    }
    __builtin_amdgcn_sched_barrier(0);

    // ---- w batch A (st=0): 8 coalesced dword loads ----
    unsigned wA[8];
    #pragma unroll
    for (int rg = 0; rg < 4; ++rg)
      #pragma unroll
      for (int p = 0; p < 2; ++p)
        wA[rg * 2 + p] = wcol[(size_t)(kt * 32 + rg * 4 + 2 * hi + p) * 1024];

    // ---- S^T = mfma(K, Q) ----
    f32x16 sa0, sa1;
    #pragma unroll
    for (int i = 0; i < 16; ++i) { sa0[i] = 0.f; sa1[i] = 0.f; }
    {
      const int sr0 = ql, sr1 = 32 + ql;
      const char* kb0 = (const char*)Ks[c] + sr0 * 128;
      const char* kb1 = (const char*)Ks[c] + sr1 * 128;
      const int sz0 = (sr0 & 7) << 4, sz1 = (sr1 & 7) << 4;
      __builtin_amdgcn_s_setprio(1);
      #pragma unroll
      for (int es = 0; es < 4; ++es) {
        short8 ka0 = *(const short8*)(kb0 + ((es * 32 + hi * 16) ^ sz0));
        short8 ka1 = *(const short8*)(kb1 + ((es * 32 + hi * 16) ^ sz1));
        sa0 = __builtin_amdgcn_mfma_f32_32x32x16_bf16(ka0, qb[es], sa0, 0, 0, 0);
        sa1 = __builtin_amdgcn_mfma_f32_32x32x16_bf16(ka1, qb[es], sa1, 0, 0, 0);
      }
      __builtin_amdgcn_s_setprio(0);
    }

    // ---- logits st=0 (consumes wA), then reload wA for st=1 ----
    float lg[32];
    #pragma unroll
    for (int rg = 0; rg < 4; ++rg) {
      const unsigned wlo = wA[rg * 2], whi = wA[rg * 2 + 1];
      lg[rg * 4 + 0] = sa0[rg * 4 + 0] * bflo(wlo);
      lg[rg * 4 + 1] = sa0[rg * 4 + 1] * bfhi(wlo);
      lg[rg * 4 + 2] = sa0[rg * 4 + 2] * bflo(whi);
      lg[rg * 4 + 3] = sa0[rg * 4 + 3] * bfhi(whi);
    }
    __builtin_amdgcn_sched_barrier(0);   // keep batch-B loads below (reg cap)
    #pragma unroll
    for (int rg = 0; rg < 4; ++rg)
      #pragma unroll
      for (int p = 0; p < 2; ++p)
        wA[rg * 2 + p] = wcol[(size_t)(kt * 32 + 16 + rg * 4 + 2 * hi + p) * 1024];
    #pragma unroll
    for (int rg = 0; rg < 4; ++rg) {
      const unsigned wlo = wA[rg * 2], whi = wA[rg * 2 + 1];
      lg[16 + rg * 4 + 0] = sa1[rg * 4 + 0] * bflo(wlo);
      lg[16 + rg * 4 + 1] = sa1[rg * 4 + 1] * bfhi(wlo);
      lg[16 + rg * 4 + 2] = sa1[rg * 4 + 2] * bflo(whi);
      lg[16 + rg * 4 + 3] = sa1[rg * 4 + 3] * bfhi(whi);
    }

    // ---- max tree + one cross-half shfl ----
    float t16[16];
    #pragma unroll
    for (int i = 0; i < 16; ++i) t16[i] = fmaxf(lg[i], lg[i + 16]);
    float t8[8];
    #pragma unroll
    for (int i = 0; i < 8; ++i) t8[i] = fmaxf(t16[i], t16[i + 8]);
    float t4[4];
    #pragma unroll
    for (int i = 0; i < 4; ++i) t4[i] = fmaxf(t8[i], t8[i + 4]);
    float pmax = fmaxf(fmaxf(t4[0], t4[1]), fmaxf(t4[2], t4[3]));
    pmax = fmaxf(pmax, __shfl_xor(pmax, 32));

    // ---- T13 defer-max (log2 domain: p <= 2^11) ----
    if (!__all(pmax <= m_r + 11.0f)) {
      const float mnew = fmaxf(m_r, pmax);
      const float corr = ex2(m_r - mnew);
      m_r = mnew;
      l_r *= corr;
      if (lane < 32) Sc[wv * 32 + ql] = corr;
      #pragma unroll
      for (int reg = 0; reg < 16; ++reg) {
        const float cr = Sc[wv * 32 + ((reg & 3) + 8 * (reg >> 2) + 4 * hi)];
        o0[reg] *= cr; o1[reg] *= cr;
      }
    }

    // ---- p = 2^(lg - m), rowsum ----
    float p[32];
    #pragma unroll
    for (int i = 0; i < 32; ++i) p[i] = ex2(lg[i] - m_r);
    float s16[16];
    #pragma unroll
    for (int i = 0; i < 16; ++i) s16[i] = p[i] + p[i + 16];
    float s8[8];
    #pragma unroll
    for (int i = 0; i < 8; ++i) s8[i] = s16[i] + s16[i + 8];
    float s4[4];
    #pragma unroll
    for (int i = 0; i < 4; ++i) s4[i] = s8[i] + s8[i + 4];
    float rs = (s4[0] + s4[1]) + (s4[2] + s4[3]);
    rs += __shfl_xor(rs, 32);
    l_r += rs;

    // ---- PV, per-ks pack+exchange+mfma (low transient registers) ----
    const int d0 = ql, d1 = 32 + ql;
    const char* vb0 = (const char*)Vt[c] + d0 * 128;
    const char* vb1 = (const char*)Vt[c] + d1 * 128;
    const int vz0 = (((d0 & 7) ^ (d0 >> 3)) & 7) << 4;
    const int vz1 = (((d1 & 7) ^ (d1 >> 3)) & 7) << 4;
    __builtin_amdgcn_s_setprio(1);
    #pragma unroll
    for (int ks = 0; ks < 4; ++ks) {
      const unsigned c0 = pk2(p[8 * ks + 0], p[8 * ks + 1]);
      const unsigned c1 = pk2(p[8 * ks + 2], p[8 * ks + 3]);
      const unsigned c2 = pk2(p[8 * ks + 4], p[8 * ks + 5]);
      const unsigned c3 = pk2(p[8 * ks + 6], p[8 * ks + 7]);
      const unsigned e0 = __shfl_xor(hi ? c0 : c2, 32);
      const unsigned e1 = __shfl_xor(hi ? c1 : c3, 32);
      uint4 dw;
      dw.x = hi ? e0 : c0;
      dw.y = hi ? e1 : c1;
      dw.z = hi ? c2 : e0;
      dw.w = hi ? c3 : e1;
      const short8 pa = __builtin_bit_cast(short8, dw);
      short8 bf0 = *(const short8*)(vb0 + ((ks * 32 + hi * 16) ^ vz0));
      short8 bf1 = *(const short8*)(vb1 + ((ks * 32 + hi * 16) ^ vz1));
      o0 = __builtin_amdgcn_mfma_f32_32x32x16_bf16(pa, bf0, o0, 0, 0, 0);
      o1 = __builtin_amdgcn_mfma_f32_32x32x16_bf16(pa, bf1, o1, 0, 0, 0);
    }
    __builtin_amdgcn_s_setprio(0);

    __syncthreads();   // buf c consumed; glds for c^1 drained here
  }

  // ---- epilogue ----
  if (lane < 32) Sc[wv * 32 + ql] = l_r;
  #pragma unroll
  for (int reg = 0; reg < 16; ++reg) {
    const int qq = (reg & 3) + 8 * (reg >> 2) + 4 * hi;
    const float lv = Sc[wv * 32 + qq];
    const float inv = 1.0f / lv;
    float* op = O + ((size_t)(b * 1024 + qblk * 128 + wv * 32 + qq)) * 512 + h * 64 + ql;
    op[0]  = o0[reg] * inv;
    op[32] = o1[reg] * inv;
  }
}

extern "C" void kernel_launch(void* const* d_in, const int* in_sizes, int n_in,
                              void* d_out, int out_size, void* d_ws, size_t ws_size,
                              hipStream_t stream) {
  const float* Q   = (const float*)d_in[0];
  const float* K   = (const float*)d_in[1];
  const float* V   = (const float*)d_in[2];
  const float* WM  = (const float*)d_in[3];
  const float* TAU = (const float*)d_in[4];
  float* out = (float*)d_out;

  unsigned*       Wt2 = (unsigned*)d_ws;                                // 4 MB
  unsigned short* KP  = (unsigned short*)((char*)d_ws + (4ull << 20));  // 16 MB
  unsigned short* VP  = (unsigned short*)((char*)d_ws + (20ull << 20)); // 16 MB

  prep_fused_kernel<<<dim3(2112), dim3(256), 0, stream>>>(K, V, WM, TAU, KP, VP, Wt2);
  attn_fast_kernel<<<dim3(1024), dim3(256), 0, stream>>>(Q, KP, VP, Wt2, out);
}